// Round 3
// baseline (342.719 us; speedup 1.0000x reference)
//
#include <hip/hip_runtime.h>
#include <hip/hip_bf16.h>

#define T_TOK 16384
#define DM 1024
#define DFF 4096
#define NE 8
#define CAP 320
#define RP 384   // per-expert padded rows (3 x 128 tiles)

typedef __attribute__((ext_vector_type(8))) short bf16x8;
typedef __attribute__((ext_vector_type(4))) float f32x4;

__device__ __forceinline__ unsigned short f2bf(float f) {
    unsigned int u = __builtin_bit_cast(unsigned int, f);
    u += 0x7FFFu + ((u >> 16) & 1u);   // round-to-nearest-even (finite inputs)
    return (unsigned short)(u >> 16);
}

__device__ __forceinline__ void store_out(unsigned short* p, float v) { *p = f2bf(v); }
__device__ __forceinline__ void store_out(float* p, float v) { *p = v; }

__device__ __forceinline__ void gload_lds16(const void* g, void* l) {
    __builtin_amdgcn_global_load_lds(
        (const __attribute__((address_space(1))) unsigned int*)g,
        (__attribute__((address_space(3))) unsigned int*)l,
        16, 0, 0);
}

// ---------------- init ----------------
__global__ void k_init(float* sumprob) {
    if (threadIdx.x < NE) sumprob[threadIdx.x] = 0.f;
}

// ---------------- router: logits, softmax, argmax, prob sums ----------------
__global__ __launch_bounds__(256) void k_router(
    const float* __restrict__ x, const float* __restrict__ rw,
    const float* __restrict__ rb, int* __restrict__ eidx,
    float* __restrict__ sumprob)
{
    __shared__ float w[DM * NE];
    for (int i = threadIdx.x; i < DM * NE; i += 256) w[i] = rw[i];
    __syncthreads();

    int t = blockIdx.x * 256 + threadIdx.x;
    float a[NE];
    #pragma unroll
    for (int e = 0; e < NE; ++e) a[e] = rb[e];

    const float4* xr = reinterpret_cast<const float4*>(x + (size_t)t * DM);
    for (int kk = 0; kk < DM / 4; ++kk) {
        float4 xv = xr[kk];
        #pragma unroll
        for (int c = 0; c < 4; ++c) {
            float xs = (c == 0) ? xv.x : (c == 1) ? xv.y : (c == 2) ? xv.z : xv.w;
            const float4* wr = reinterpret_cast<const float4*>(&w[(kk * 4 + c) * NE]);
            float4 w0 = wr[0], w1 = wr[1];
            a[0] += xs * w0.x; a[1] += xs * w0.y; a[2] += xs * w0.z; a[3] += xs * w0.w;
            a[4] += xs * w1.x; a[5] += xs * w1.y; a[6] += xs * w1.z; a[7] += xs * w1.w;
        }
    }

    float m = a[0]; int bi = 0;
    #pragma unroll
    for (int e = 1; e < NE; ++e) if (a[e] > m) { m = a[e]; bi = e; }

    float p[NE], s = 0.f;
    #pragma unroll
    for (int e = 0; e < NE; ++e) { p[e] = __expf(a[e] - m); s += p[e]; }
    float inv = 1.f / s;
    eidx[t] = bi;

    #pragma unroll
    for (int e = 0; e < NE; ++e) {
        float v = p[e] * inv;
        #pragma unroll
        for (int o = 32; o > 0; o >>= 1) v += __shfl_down(v, o);
        if ((threadIdx.x & 63) == 0) atomicAdd(&sumprob[e], v);
    }
}

// ---------------- per-expert sequential rank scan ----------------
__global__ __launch_bounds__(256) void k_scan(
    const int* __restrict__ eidx, int* __restrict__ token_slot,
    int* __restrict__ s2t, int* __restrict__ counts)
{
    const int e = blockIdx.x;
    const int tid = threadIdx.x, lane = tid & 63, w = tid >> 6;
    __shared__ int wts[4];

    for (int i = tid; i < CAP; i += 256) s2t[e * CAP + i] = -1;
    __syncthreads();

    int running = 0;
    for (int base = 0; base < T_TOK; base += 256) {
        int t = base + tid;
        bool flag = (eidx[t] == e);
        unsigned long long mask = __ballot(flag);
        int wp = __popcll(mask & ((1ull << lane) - 1ull));
        if (lane == 0) wts[w] = __popcll(mask);
        __syncthreads();
        int woff = 0, btot = 0;
        #pragma unroll
        for (int j = 0; j < 4; ++j) { int v = wts[j]; btot += v; if (j < w) woff += v; }
        if (flag) {
            int rank = running + woff + wp;
            if (rank < CAP) {
                token_slot[t] = e * CAP + rank;
                s2t[e * CAP + rank] = t;
            } else {
                token_slot[t] = -1;
            }
        }
        running += btot;
        __syncthreads();
    }
    if (tid == 0) counts[e] = running;
}

// ---------------- load-balance loss ----------------
__global__ void k_lb(const int* __restrict__ counts, const float* __restrict__ sumprob,
                     float* __restrict__ out_lb)
{
    if (threadIdx.x == 0) {
        float acc = 0.f;
        for (int e = 0; e < NE; ++e) acc += (float)counts[e] * sumprob[e];
        *out_lb = (float)NE * acc / ((float)T_TOK * (float)T_TOK);
    }
}

// ---------------- gather kept tokens -> bf16 buffer (zero padding rows) ----------------
__global__ __launch_bounds__(256) void k_gather(
    const float* __restrict__ x, const int* __restrict__ s2t,
    unsigned short* __restrict__ xb)
{
    int r = blockIdx.x;               // 0 .. NE*RP-1
    int e = r / RP, i = r - e * RP;
    int tok = (i < CAP) ? s2t[e * CAP + i] : -1;
    int tid = threadIdx.x;
    unsigned short* dst = xb + (size_t)r * DM + tid * 4;
    if (tok >= 0) {
        float4 v = reinterpret_cast<const float4*>(x + (size_t)tok * DM)[tid];
        short4 b = make_short4((short)f2bf(v.x), (short)f2bf(v.y),
                               (short)f2bf(v.z), (short)f2bf(v.w));
        *reinterpret_cast<short4*>(dst) = b;
    } else {
        *reinterpret_cast<short4*>(dst) = make_short4(0, 0, 0, 0);
    }
}

// ---------------- grouped GEMM: C[e] = act(A[e] @ B[e] + bias[e]) ----------------
// A: bf16 [NE][RP][K] row-major. B: f32 [NE][K][N] row-major (cvt to bf16 in
// reg-staged prefetch). 4 waves 2x2; each wave owns (MF*16)x(NF*16) output.
// LDS layout [row][kgrp] (64B rows) -> fragment ds_read_b128 is bank-uniform
// and matches global_load_lds linear (base + lane*16) write order for A.
// MFMA 16x16x32 bf16: A-frag lane: row=lane&15, k=8*(lane>>4)+j
//                     C/D:        col=lane&15, row=4*(lane>>4)+i
template<int MF, int NF, bool RELU, typename OutT>
__global__ __launch_bounds__(256, 2) void k_gemm(
    const unsigned short* __restrict__ A, const float* __restrict__ B,
    const float* __restrict__ bias, OutT* __restrict__ C,
    int K, int N)
{
    constexpr int BM = 2 * MF * 16;   // 128
    constexpr int BN = 2 * NF * 16;   // 128
    constexpr int CA = (BM * 4) / 256;  // A 16B chunks per thread (2)
    constexpr int CB = (BN * 4) / 256;  // B slots per thread (2)

    __shared__ bf16x8 lA[2][BM][4];   // [buf][row][kgrp]
    __shared__ bf16x8 lB[2][BN][4];   // [buf][col][kgrp]

    const int e  = blockIdx.z;
    const int m0 = blockIdx.y * BM;
    const int n0 = blockIdx.x * BN;
    const int tid = threadIdx.x, lane = tid & 63;
    const int w = tid >> 6, wm = w >> 1, wn = w & 1;
    const int lrow = lane & 15, kg = lane >> 4;

    const unsigned short* Ae = A + (size_t)e * RP * K;
    const float* Be = B + (size_t)e * K * N;

    // ---- staging helpers ----
    auto stage_A = [&](int buf, int k0) {
        bf16x8* lab = &lA[buf][0][0];
        #pragma unroll
        for (int c = 0; c < CA; ++c) {
            int base = c * 256 + w * 64;           // wave-uniform chunk base
            int idx = base + lane;                 // this lane's chunk
            const unsigned short* src =
                Ae + (size_t)(m0 + (idx >> 2)) * K + k0 + (idx & 3) * 8;
            gload_lds16(src, lab + base);
        }
    };
    auto load_B = [&](int k0, float br[CB][8]) {
        #pragma unroll
        for (int c = 0; c < CB; ++c) {
            int idx = c * 256 + tid;
            int col = idx & (BN - 1), q = idx / BN;
            const float* bp = Be + (size_t)(k0 + q * 8) * N + n0 + col;
            #pragma unroll
            for (int j = 0; j < 8; ++j) br[c][j] = bp[(size_t)j * N];
        }
    };
    auto write_B = [&](int buf, float br[CB][8]) {
        #pragma unroll
        for (int c = 0; c < CB; ++c) {
            int idx = c * 256 + tid;
            int col = idx & (BN - 1), q = idx / BN;
            bf16x8 v;
            #pragma unroll
            for (int j = 0; j < 8; ++j) v[j] = (short)f2bf(br[c][j]);
            lB[buf][col][q] = v;
        }
    };

    f32x4 acc[MF][NF] = {};

    // prologue: stage tile 0
    float br[CB][8], brn[CB][8];
    stage_A(0, 0);
    load_B(0, br);
    write_B(0, br);
    __syncthreads();   // drains vmcnt(0) -> A tile 0 in LDS too

    const int nk = K / 32;
    int cur = 0;
    for (int ks = 0; ks < nk; ++ks) {
        const bool more = (ks + 1 < nk);
        if (more) {
            stage_A(cur ^ 1, (ks + 1) * 32);   // async -> LDS buf^1
            load_B((ks + 1) * 32, brn);        // issue f32 loads -> regs
        }

        bf16x8 af[MF], bfr[NF];
        #pragma unroll
        for (int m = 0; m < MF; ++m) af[m] = lA[cur][wm * MF * 16 + m * 16 + lrow][kg];
        #pragma unroll
        for (int n = 0; n < NF; ++n) bfr[n] = lB[cur][wn * NF * 16 + n * 16 + lrow][kg];
        #pragma unroll
        for (int m = 0; m < MF; ++m)
            #pragma unroll
            for (int n = 0; n < NF; ++n)
                acc[m][n] = __builtin_amdgcn_mfma_f32_16x16x32_bf16(
                    af[m], bfr[n], acc[m][n], 0, 0, 0);

        if (more) write_B(cur ^ 1, brn);       // cvt + LDS write (buf^1)
        __syncthreads();                       // one barrier per K-step
        cur ^= 1;
    }

    #pragma unroll
    for (int n = 0; n < NF; ++n) {
        int col = n0 + wn * NF * 16 + n * 16 + lrow;
        float bv = bias[e * N + col];
        #pragma unroll
        for (int m = 0; m < MF; ++m) {
            int rbase = m0 + wm * MF * 16 + m * 16 + kg * 4;
            #pragma unroll
            for (int i = 0; i < 4; ++i) {
                float v = acc[m][n][i] + bv;
                if (RELU) v = fmaxf(v, 0.f);
                store_out(C + ((size_t)e * RP + rbase + i) * (size_t)N + col, v);
            }
        }
    }
}

// ---------------- scatter back (zeros for dropped) ----------------
__global__ __launch_bounds__(256) void k_scatter(
    const float* __restrict__ y, const int* __restrict__ token_slot,
    float* __restrict__ out)
{
    int t = blockIdx.x;
    int slot = token_slot[t];
    float4* o = reinterpret_cast<float4*>(out + (size_t)t * DM);
    if (slot >= 0) {
        int e = slot / CAP, i = slot - e * CAP;
        o[threadIdx.x] = reinterpret_cast<const float4*>(
            y + ((size_t)e * RP + i) * DM)[threadIdx.x];
    } else {
        o[threadIdx.x] = make_float4(0.f, 0.f, 0.f, 0.f);
    }
}

extern "C" void kernel_launch(void* const* d_in, const int* in_sizes, int n_in,
                              void* d_out, int out_size, void* d_ws, size_t ws_size,
                              hipStream_t stream)
{
    const float* x  = (const float*)d_in[0];
    const float* rw = (const float*)d_in[1];
    const float* rb = (const float*)d_in[2];
    const float* w1 = (const float*)d_in[3];
    const float* b1 = (const float*)d_in[4];
    const float* w2 = (const float*)d_in[5];
    const float* b2 = (const float*)d_in[6];
    float* out = (float*)d_out;

    char* ws = (char*)d_ws;
    int*   eidx       = (int*)(ws);                        // 16384 int
    int*   token_slot = (int*)(ws + 65536);                // 16384 int
    int*   s2t        = (int*)(ws + 131072);               // 2560 int
    int*   counts     = (int*)(ws + 141312);               // 8 int
    float* sumprob    = (float*)(ws + 141376);             // 8 f32
    unsigned short* xb = (unsigned short*)(ws + 147456);                       // [NE][RP][DM] bf16
    unsigned short* h  = (unsigned short*)(ws + 147456 + 6291456);             // [NE][RP][DFF] bf16
    float*          y  = (float*)(ws + 147456 + 6291456 + 25165824);           // [NE][RP][DM] f32

    hipLaunchKernelGGL(k_init, dim3(1), dim3(64), 0, stream, sumprob);
    hipLaunchKernelGGL(k_router, dim3(T_TOK / 256), dim3(256), 0, stream,
                       x, rw, rb, eidx, sumprob);
    hipLaunchKernelGGL(k_scan, dim3(NE), dim3(256), 0, stream,
                       eidx, token_slot, s2t, counts);
    hipLaunchKernelGGL(k_lb, dim3(1), dim3(64), 0, stream,
                       counts, sumprob, out + (size_t)T_TOK * DM);
    hipLaunchKernelGGL(k_gather, dim3(NE * RP), dim3(256), 0, stream, x, s2t, xb);
    hipLaunchKernelGGL((k_gemm<4, 4, true, unsigned short>),
                       dim3(DFF / 128, RP / 128, NE), dim3(256), 0, stream,
                       xb, w1, b1, h, DM, DFF);
    hipLaunchKernelGGL((k_gemm<4, 4, false, float>),
                       dim3(DM / 128, RP / 128, NE), dim3(256), 0, stream,
                       h, w2, b2, y, DFF, DM);
    hipLaunchKernelGGL(k_scatter, dim3(T_TOK), dim3(256), 0, stream,
                       y, token_slot, out);
}

// Round 4
// 313.301 us; speedup vs baseline: 1.0939x; 1.0939x over previous
//
#include <hip/hip_runtime.h>
#include <hip/hip_bf16.h>

#define T_TOK 16384
#define DM 1024
#define DFF 4096
#define NE 8
#define CAP 320
#define RP 384   // per-expert padded rows (3 x 128 tiles)

typedef __attribute__((ext_vector_type(8))) short bf16x8;
typedef __attribute__((ext_vector_type(4))) float f32x4;

__device__ __forceinline__ unsigned short f2bf(float f) {
    unsigned int u = __builtin_bit_cast(unsigned int, f);
    u += 0x7FFFu + ((u >> 16) & 1u);   // round-to-nearest-even (finite inputs)
    return (unsigned short)(u >> 16);
}

__device__ __forceinline__ void store_out(unsigned short* p, float v) { *p = f2bf(v); }
__device__ __forceinline__ void store_out(float* p, float v) { *p = v; }

__device__ __forceinline__ void gload_lds16(const void* g, void* l) {
    __builtin_amdgcn_global_load_lds(
        (const __attribute__((address_space(1))) unsigned int*)g,
        (__attribute__((address_space(3))) unsigned int*)l,
        16, 0, 0);
}

// ---------------- init ----------------
__global__ void k_init(float* sumprob) {
    if (threadIdx.x < NE) sumprob[threadIdx.x] = 0.f;
}

// ---------------- router: logits, softmax, argmax, prob sums ----------------
__global__ __launch_bounds__(256) void k_router(
    const float* __restrict__ x, const float* __restrict__ rw,
    const float* __restrict__ rb, int* __restrict__ eidx,
    float* __restrict__ sumprob)
{
    __shared__ float w[DM * NE];
    for (int i = threadIdx.x; i < DM * NE; i += 256) w[i] = rw[i];
    __syncthreads();

    int t = blockIdx.x * 256 + threadIdx.x;
    float a[NE];
    #pragma unroll
    for (int e = 0; e < NE; ++e) a[e] = rb[e];

    const float4* xr = reinterpret_cast<const float4*>(x + (size_t)t * DM);
    for (int kk = 0; kk < DM / 4; ++kk) {
        float4 xv = xr[kk];
        #pragma unroll
        for (int c = 0; c < 4; ++c) {
            float xs = (c == 0) ? xv.x : (c == 1) ? xv.y : (c == 2) ? xv.z : xv.w;
            const float4* wr = reinterpret_cast<const float4*>(&w[(kk * 4 + c) * NE]);
            float4 w0 = wr[0], w1 = wr[1];
            a[0] += xs * w0.x; a[1] += xs * w0.y; a[2] += xs * w0.z; a[3] += xs * w0.w;
            a[4] += xs * w1.x; a[5] += xs * w1.y; a[6] += xs * w1.z; a[7] += xs * w1.w;
        }
    }

    float m = a[0]; int bi = 0;
    #pragma unroll
    for (int e = 1; e < NE; ++e) if (a[e] > m) { m = a[e]; bi = e; }

    float p[NE], s = 0.f;
    #pragma unroll
    for (int e = 0; e < NE; ++e) { p[e] = __expf(a[e] - m); s += p[e]; }
    float inv = 1.f / s;
    eidx[t] = bi;

    #pragma unroll
    for (int e = 0; e < NE; ++e) {
        float v = p[e] * inv;
        #pragma unroll
        for (int o = 32; o > 0; o >>= 1) v += __shfl_down(v, o);
        if ((threadIdx.x & 63) == 0) atomicAdd(&sumprob[e], v);
    }
}

// ---------------- per-expert sequential rank scan ----------------
__global__ __launch_bounds__(256) void k_scan(
    const int* __restrict__ eidx, int* __restrict__ token_slot,
    int* __restrict__ s2t, int* __restrict__ counts)
{
    const int e = blockIdx.x;
    const int tid = threadIdx.x, lane = tid & 63, w = tid >> 6;
    __shared__ int wts[4];

    for (int i = tid; i < CAP; i += 256) s2t[e * CAP + i] = -1;
    __syncthreads();

    int running = 0;
    for (int base = 0; base < T_TOK; base += 256) {
        int t = base + tid;
        bool flag = (eidx[t] == e);
        unsigned long long mask = __ballot(flag);
        int wp = __popcll(mask & ((1ull << lane) - 1ull));
        if (lane == 0) wts[w] = __popcll(mask);
        __syncthreads();
        int woff = 0, btot = 0;
        #pragma unroll
        for (int j = 0; j < 4; ++j) { int v = wts[j]; btot += v; if (j < w) woff += v; }
        if (flag) {
            int rank = running + woff + wp;
            if (rank < CAP) {
                token_slot[t] = e * CAP + rank;
                s2t[e * CAP + rank] = t;
            } else {
                token_slot[t] = -1;
            }
        }
        running += btot;
        __syncthreads();
    }
    if (tid == 0) counts[e] = running;
}

// ---------------- load-balance loss ----------------
__global__ void k_lb(const int* __restrict__ counts, const float* __restrict__ sumprob,
                     float* __restrict__ out_lb)
{
    if (threadIdx.x == 0) {
        float acc = 0.f;
        for (int e = 0; e < NE; ++e) acc += (float)counts[e] * sumprob[e];
        *out_lb = (float)NE * acc / ((float)T_TOK * (float)T_TOK);
    }
}

// ---------------- gather kept tokens -> bf16 buffer (zero padding rows) ----------------
__global__ __launch_bounds__(256) void k_gather(
    const float* __restrict__ x, const int* __restrict__ s2t,
    unsigned short* __restrict__ xb)
{
    int r = blockIdx.x;               // 0 .. NE*RP-1
    int e = r / RP, i = r - e * RP;
    int tok = (i < CAP) ? s2t[e * CAP + i] : -1;
    int tid = threadIdx.x;
    unsigned short* dst = xb + (size_t)r * DM + tid * 4;
    if (tok >= 0) {
        float4 v = reinterpret_cast<const float4*>(x + (size_t)tok * DM)[tid];
        short4 b = make_short4((short)f2bf(v.x), (short)f2bf(v.y),
                               (short)f2bf(v.z), (short)f2bf(v.w));
        *reinterpret_cast<short4*>(dst) = b;
    } else {
        *reinterpret_cast<short4*>(dst) = make_short4(0, 0, 0, 0);
    }
}

// ---------------- grouped GEMM: C[e] = act(A[e] @ B[e] + bias[e]) ----------------
// A: bf16 [NE][RP][K] row-major, staged via global_load_lds into lA[buf][row][q]
//    (linear dest; fragment read bank-aggregate-minimal).
// B: f32 [NE][K][N], 2-K-step-deep register prefetch -> cvt -> lB[buf][q][col]
//    (+1 slot pad: write lane-contiguous = conflict-free; read 4-bank staggered).
// Sync: counted-vmcnt raw barrier (T4). Per iter issue order: stage_A(ks+1)
//    [2 ops, oldest] then load_B(ks+2) [CB*8 ops, stay in flight across the
//    barrier]. s_waitcnt vmcnt(CB*8) drains only stage_A. lgkmcnt(0) flushes
//    ds_writes before s_barrier. stage_A/write_B target buf^1, disjoint from
//    the buf being read, so one barrier per K-step suffices.
// MFMA 16x16x32 bf16: A-frag lane: row=lane&15, k=8*(lane>>4)+j
//                     C/D:        col=lane&15, row=4*(lane>>4)+i
template<int MF, int NF, bool RELU, typename OutT>
__global__ __launch_bounds__(256, 2) void k_gemm(
    const unsigned short* __restrict__ A, const float* __restrict__ B,
    const float* __restrict__ bias, OutT* __restrict__ C,
    int K, int N)
{
    constexpr int BM = 2 * MF * 16;     // 128
    constexpr int BN = 2 * NF * 16;     // 128 or 64
    constexpr int CA = (BM * 4) / 256;  // A 16B chunks per thread (2)
    constexpr int CB = (BN * 4) / 256;  // B slots per thread (2 or 1)

    __shared__ bf16x8 lA[2][BM][4];       // [buf][row][kgrp]
    __shared__ bf16x8 lB[2][4][BN + 1];   // [buf][kgrp][col] (+1 pad -> 4-bank stagger)

    const int e  = blockIdx.z;
    const int m0 = blockIdx.y * BM;
    const int n0 = blockIdx.x * BN;
    const int tid = threadIdx.x, lane = tid & 63;
    const int w = tid >> 6, wm = w >> 1, wn = w & 1;
    const int lrow = lane & 15, kg = lane >> 4;

    const unsigned short* Ae = A + (size_t)e * RP * K;
    const float* Be = B + (size_t)e * K * N;

    // bias first: oldest in vmcnt queue, done before any counted wait matters
    float bv[NF];
    #pragma unroll
    for (int n = 0; n < NF; ++n)
        bv[n] = bias[e * N + n0 + wn * NF * 16 + n * 16 + lrow];

    auto stage_A = [&](int buf, int k0) {
        bf16x8* lab = &lA[buf][0][0];
        #pragma unroll
        for (int c = 0; c < CA; ++c) {
            int base = c * 256 + w * 64;           // wave-uniform chunk base
            int idx = base + lane;
            const unsigned short* src =
                Ae + (size_t)(m0 + (idx >> 2)) * K + k0 + (idx & 3) * 8;
            gload_lds16(src, lab + base);
        }
    };
    auto load_B = [&](int k0, float br[CB][8]) {
        #pragma unroll
        for (int c = 0; c < CB; ++c) {
            int idx = c * 256 + tid;
            int col = idx & (BN - 1), q = idx / BN;
            const float* bp = Be + (size_t)(k0 + q * 8) * N + n0 + col;
            #pragma unroll
            for (int j = 0; j < 8; ++j) br[c][j] = bp[(size_t)j * N];
        }
    };
    auto write_B = [&](int buf, float br[CB][8]) {
        #pragma unroll
        for (int c = 0; c < CB; ++c) {
            int idx = c * 256 + tid;
            int col = idx & (BN - 1), q = idx / BN;
            bf16x8 v;
            #pragma unroll
            for (int j = 0; j < 8; ++j) v[j] = (short)f2bf(br[c][j]);
            lB[buf][q][col] = v;
        }
    };

    f32x4 acc[MF][NF] = {};
    float brX[CB][8], brY[CB][8];
    const int nk = K / 32;

    // ---- prologue ----
    load_B(0, brX);          // B(0) -> regs
    stage_A(0, 0);           // A(0) -> LDS (older than load_B(1))
    write_B(0, brX);         // compiler waits brX loads; cvt; ds_write
    load_B(32, brX);         // B(1) in flight
    asm volatile("s_waitcnt vmcnt(%0) lgkmcnt(0)" :: "i"(CB * 8) : "memory");
    __builtin_amdgcn_s_barrier();
    __builtin_amdgcn_sched_barrier(0);

    // body(cur, brW=B(ks+1), brL<-B(ks+2), ks)
    auto body = [&](int cur, float (&brW)[CB][8], float (&brL)[CB][8], int ks) {
        if (ks + 1 < nk) stage_A(cur ^ 1, (ks + 1) * 32);  // oldest vmem this iter
        if (ks + 2 < nk) load_B((ks + 2) * 32, brL);       // stays in flight

        bf16x8 af[MF], bfr[NF];
        #pragma unroll
        for (int m = 0; m < MF; ++m) af[m] = lA[cur][wm * MF * 16 + m * 16 + lrow][kg];
        #pragma unroll
        for (int n = 0; n < NF; ++n) bfr[n] = lB[cur][kg][wn * NF * 16 + n * 16 + lrow];
        #pragma unroll
        for (int m = 0; m < MF; ++m)
            #pragma unroll
            for (int n = 0; n < NF; ++n)
                acc[m][n] = __builtin_amdgcn_mfma_f32_16x16x32_bf16(
                    af[m], bfr[n], acc[m][n], 0, 0, 0);

        if (ks + 1 < nk) write_B(cur ^ 1, brW);            // B(ks+1) -> LDS buf^1

        if (ks + 2 < nk) {
            asm volatile("s_waitcnt vmcnt(%0) lgkmcnt(0)" :: "i"(CB * 8) : "memory");
        } else {
            asm volatile("s_waitcnt vmcnt(0) lgkmcnt(0)" ::: "memory");
        }
        __builtin_amdgcn_s_barrier();
        __builtin_amdgcn_sched_barrier(0);
    };

    for (int ks = 0; ks < nk; ks += 2) {
        body(0, brX, brY, ks);
        body(1, brY, brX, ks + 1);
    }

    #pragma unroll
    for (int n = 0; n < NF; ++n) {
        int col = n0 + wn * NF * 16 + n * 16 + lrow;
        #pragma unroll
        for (int m = 0; m < MF; ++m) {
            int rbase = m0 + wm * MF * 16 + m * 16 + kg * 4;
            #pragma unroll
            for (int i = 0; i < 4; ++i) {
                float v = acc[m][n][i] + bv[n];
                if (RELU) v = fmaxf(v, 0.f);
                store_out(C + ((size_t)e * RP + rbase + i) * (size_t)N + col, v);
            }
        }
    }
}

// ---------------- scatter back (zeros for dropped) ----------------
__global__ __launch_bounds__(256) void k_scatter(
    const float* __restrict__ y, const int* __restrict__ token_slot,
    float* __restrict__ out)
{
    int t = blockIdx.x;
    int slot = token_slot[t];
    float4* o = reinterpret_cast<float4*>(out + (size_t)t * DM);
    if (slot >= 0) {
        int e = slot / CAP, i = slot - e * CAP;
        o[threadIdx.x] = reinterpret_cast<const float4*>(
            y + ((size_t)e * RP + i) * DM)[threadIdx.x];
    } else {
        o[threadIdx.x] = make_float4(0.f, 0.f, 0.f, 0.f);
    }
}

extern "C" void kernel_launch(void* const* d_in, const int* in_sizes, int n_in,
                              void* d_out, int out_size, void* d_ws, size_t ws_size,
                              hipStream_t stream)
{
    const float* x  = (const float*)d_in[0];
    const float* rw = (const float*)d_in[1];
    const float* rb = (const float*)d_in[2];
    const float* w1 = (const float*)d_in[3];
    const float* b1 = (const float*)d_in[4];
    const float* w2 = (const float*)d_in[5];
    const float* b2 = (const float*)d_in[6];
    float* out = (float*)d_out;

    char* ws = (char*)d_ws;
    int*   eidx       = (int*)(ws);                        // 16384 int
    int*   token_slot = (int*)(ws + 65536);                // 16384 int
    int*   s2t        = (int*)(ws + 131072);               // 2560 int
    int*   counts     = (int*)(ws + 141312);               // 8 int
    float* sumprob    = (float*)(ws + 141376);             // 8 f32
    unsigned short* xb = (unsigned short*)(ws + 147456);                       // [NE][RP][DM] bf16
    unsigned short* h  = (unsigned short*)(ws + 147456 + 6291456);             // [NE][RP][DFF] bf16
    float*          y  = (float*)(ws + 147456 + 6291456 + 25165824);           // [NE][RP][DM] f32

    hipLaunchKernelGGL(k_init, dim3(1), dim3(64), 0, stream, sumprob);
    hipLaunchKernelGGL(k_router, dim3(T_TOK / 256), dim3(256), 0, stream,
                       x, rw, rb, eidx, sumprob);
    hipLaunchKernelGGL(k_scan, dim3(NE), dim3(256), 0, stream,
                       eidx, token_slot, s2t, counts);
    hipLaunchKernelGGL(k_lb, dim3(1), dim3(64), 0, stream,
                       counts, sumprob, out + (size_t)T_TOK * DM);
    hipLaunchKernelGGL(k_gather, dim3(NE * RP), dim3(256), 0, stream, x, s2t, xb);
    hipLaunchKernelGGL((k_gemm<4, 4, true, unsigned short>),
                       dim3(DFF / 128, RP / 128, NE), dim3(256), 0, stream,
                       xb, w1, b1, h, DM, DFF);
    hipLaunchKernelGGL((k_gemm<4, 2, false, float>),
                       dim3(DM / 64, RP / 128, NE), dim3(256), 0, stream,
                       h, w2, b2, y, DFF, DM);
    hipLaunchKernelGGL(k_scatter, dim3(T_TOK), dim3(256), 0, stream,
                       y, token_slot, out);
}

// Round 5
// 288.302 us; speedup vs baseline: 1.1888x; 1.0867x over previous
//
#include <hip/hip_runtime.h>

#define T_TOK 16384
#define DM 1024
#define DFF 4096
#define NE 8
#define CAP 320
#define RP 384   // per-expert padded rows (3 x 128 tiles)

typedef __attribute__((ext_vector_type(8))) short bf16x8;
typedef __attribute__((ext_vector_type(4))) float f32x4;
typedef __attribute__((ext_vector_type(4))) unsigned int u32x4;

__device__ __forceinline__ unsigned short f2bf(float f) {
    unsigned int u = __builtin_bit_cast(unsigned int, f);
    u += 0x7FFFu + ((u >> 16) & 1u);   // RNE (finite inputs)
    return (unsigned short)(u >> 16);
}

__device__ __forceinline__ void gload_lds16(const void* g, void* l) {
    __builtin_amdgcn_global_load_lds(
        (const __attribute__((address_space(1))) unsigned int*)g,
        (__attribute__((address_space(3))) unsigned int*)l,
        16, 0, 0);
}

// ---------------- init ----------------
__global__ void k_init(float* sumprob) {
    if (threadIdx.x < NE) sumprob[threadIdx.x] = 0.f;
}

// ---------------- router ----------------
__global__ __launch_bounds__(256) void k_router(
    const float* __restrict__ x, const float* __restrict__ rw,
    const float* __restrict__ rb, int* __restrict__ eidx,
    float* __restrict__ sumprob)
{
    __shared__ float w[DM * NE];
    for (int i = threadIdx.x; i < DM * NE; i += 256) w[i] = rw[i];
    __syncthreads();

    int t = blockIdx.x * 256 + threadIdx.x;
    float a[NE];
    #pragma unroll
    for (int e = 0; e < NE; ++e) a[e] = rb[e];

    const float4* xr = reinterpret_cast<const float4*>(x + (size_t)t * DM);
    for (int kk = 0; kk < DM / 4; ++kk) {
        float4 xv = xr[kk];
        #pragma unroll
        for (int c = 0; c < 4; ++c) {
            float xs = (c == 0) ? xv.x : (c == 1) ? xv.y : (c == 2) ? xv.z : xv.w;
            const float4* wr = reinterpret_cast<const float4*>(&w[(kk * 4 + c) * NE]);
            float4 w0 = wr[0], w1 = wr[1];
            a[0] += xs * w0.x; a[1] += xs * w0.y; a[2] += xs * w0.z; a[3] += xs * w0.w;
            a[4] += xs * w1.x; a[5] += xs * w1.y; a[6] += xs * w1.z; a[7] += xs * w1.w;
        }
    }

    float m = a[0]; int bi = 0;
    #pragma unroll
    for (int e = 1; e < NE; ++e) if (a[e] > m) { m = a[e]; bi = e; }

    float p[NE], s = 0.f;
    #pragma unroll
    for (int e = 0; e < NE; ++e) { p[e] = __expf(a[e] - m); s += p[e]; }
    float inv = 1.f / s;
    eidx[t] = bi;

    #pragma unroll
    for (int e = 0; e < NE; ++e) {
        float v = p[e] * inv;
        #pragma unroll
        for (int o = 32; o > 0; o >>= 1) v += __shfl_down(v, o);
        if ((threadIdx.x & 63) == 0) atomicAdd(&sumprob[e], v);
    }
}

// ---------------- per-expert sequential rank scan ----------------
__global__ __launch_bounds__(256) void k_scan(
    const int* __restrict__ eidx, int* __restrict__ token_slot,
    int* __restrict__ s2t, int* __restrict__ counts)
{
    const int e = blockIdx.x;
    const int tid = threadIdx.x, lane = tid & 63, w = tid >> 6;
    __shared__ int wts[4];

    for (int i = tid; i < CAP; i += 256) s2t[e * CAP + i] = -1;
    __syncthreads();

    int running = 0;
    for (int base = 0; base < T_TOK; base += 256) {
        int t = base + tid;
        bool flag = (eidx[t] == e);
        unsigned long long mask = __ballot(flag);
        int wp = __popcll(mask & ((1ull << lane) - 1ull));
        if (lane == 0) wts[w] = __popcll(mask);
        __syncthreads();
        int woff = 0, btot = 0;
        #pragma unroll
        for (int j = 0; j < 4; ++j) { int v = wts[j]; btot += v; if (j < w) woff += v; }
        if (flag) {
            int rank = running + woff + wp;
            if (rank < CAP) {
                token_slot[t] = e * CAP + rank;
                s2t[e * CAP + rank] = t;
            } else {
                token_slot[t] = -1;
            }
        }
        running += btot;
        __syncthreads();
    }
    if (tid == 0) counts[e] = running;
}

// ---------------- load-balance loss ----------------
__global__ void k_lb(const int* __restrict__ counts, const float* __restrict__ sumprob,
                     float* __restrict__ out_lb)
{
    if (threadIdx.x == 0) {
        float acc = 0.f;
        for (int e = 0; e < NE; ++e) acc += (float)counts[e] * sumprob[e];
        *out_lb = (float)NE * acc / ((float)T_TOK * (float)T_TOK);
    }
}

// ---------------- gather ----------------
__global__ __launch_bounds__(256) void k_gather(
    const float* __restrict__ x, const int* __restrict__ s2t,
    unsigned short* __restrict__ xb)
{
    int r = blockIdx.x;
    int e = r / RP, i = r - e * RP;
    int tok = (i < CAP) ? s2t[e * CAP + i] : -1;
    int tid = threadIdx.x;
    unsigned short* dst = xb + (size_t)r * DM + tid * 4;
    if (tok >= 0) {
        float4 v = reinterpret_cast<const float4*>(x + (size_t)tok * DM)[tid];
        short4 b = make_short4((short)f2bf(v.x), (short)f2bf(v.y),
                               (short)f2bf(v.z), (short)f2bf(v.w));
        *reinterpret_cast<short4*>(dst) = b;
    } else {
        *reinterpret_cast<short4*>(dst) = make_short4(0, 0, 0, 0);
    }
}

// ---------------- zero y ----------------
__global__ __launch_bounds__(256) void k_zero(float4* __restrict__ p, int n4) {
    for (int i = blockIdx.x * 256 + threadIdx.x; i < n4; i += gridDim.x * 256)
        p[i] = make_float4(0.f, 0.f, 0.f, 0.f);
}

// ---------------- grouped GEMM, 128x128 tile, deep-pipelined ----------------
// A: bf16 [NE][RP][RS], cols kb0..kb0+NK*32. Staged 2-ahead via global_load_lds
//    into a 3-buffer LDS ring lA[3][128][4] (linear dest).
// B: f32 [NE][RS][N], rows kb0..; reg-loaded 2 iters ahead (brX/brY ping-pong),
//    cvt_pk -> bf16, written to lB[2][4][BN+1] (padded, write conflict-free).
// Sync ledger (per steady iter k): issue A(k+2)[2 ops] then B(k+2)[16 ops].
//    write_B(k+1) reg-dep auto-drains B(k+1) & older (incl. A(k+1)).
//    End-of-iter wait: vmcnt(18)=A(k+2)+B(k+2) in flight, lgkmcnt(0), s_barrier.
//    A staged at k is read at k+2 (drained end of k+1); lB written at k is read
//    at k+1; buffer being written is never the one being read. No sched_barrier
//    (m141: order-pinning regresses ~40%).
// MFMA 16x16x32 bf16: A-frag row=lane&15, k=8*(lane>>4)+j; C/D col=lane&15,
//    row=4*(lane>>4)+i.
template<int NK, int RS, int N, bool RELU, bool ATOMIC, typename OutT>
__global__ __launch_bounds__(256, 2) void k_gemm(
    const unsigned short* __restrict__ A, const float* __restrict__ B,
    const float* __restrict__ bias, OutT* __restrict__ C)
{
    constexpr int MF = 4, NF = 4;
    constexpr int BM = 128, BN = 128;
    constexpr int CB = 2;                         // B slots per thread
    constexpr int NTILES = N / BN;
    constexpr int MAIN = ((NK - 2) / 6) * 6;      // main-loop iters (mult of 6)

    __shared__ bf16x8 lA[3][BM][4];               // [slot][row][kgrp]
    __shared__ bf16x8 lB[2][4][BN + 1];           // [buf][kgrp][col] (+1 pad)

    const int gx = blockIdx.x;
    const int e  = blockIdx.z;
    const int m0 = blockIdx.y * BM;
    const int n0 = (gx % NTILES) * BN;
    const int kb0 = (gx / NTILES) * (NK * 32);
    const int tid = threadIdx.x, lane = tid & 63;
    const int w = tid >> 6, wm = w >> 1, wn = w & 1;
    const int lrow = lane & 15, kg = lane >> 4;

    const unsigned short* Ae = A + (size_t)e * RP * RS + kb0;
    const float* Be = B + ((size_t)e * RS + kb0) * N;

    float bv[NF];
    #pragma unroll
    for (int n = 0; n < NF; ++n)
        bv[n] = (kb0 == 0 && bias) ? bias[e * N + n0 + wn * NF * 16 + n * 16 + lrow] : 0.f;

    auto stage_A = [&](int ks, int slot) {
        bf16x8* lab = &lA[slot][0][0];
        #pragma unroll
        for (int c = 0; c < 2; ++c) {
            int base = c * 256 + w * 64;          // wave-uniform chunk base
            int idx = base + lane;
            const unsigned short* src =
                Ae + (size_t)(m0 + (idx >> 2)) * RS + ks * 32 + (idx & 3) * 8;
            gload_lds16(src, lab + base);
        }
    };
    auto load_B = [&](int ks, float (&br)[CB][8]) {
        #pragma unroll
        for (int c = 0; c < CB; ++c) {
            int idx = c * 256 + tid;
            int col = idx & (BN - 1), q = idx / BN;
            const float* bp = Be + (size_t)(ks * 32 + q * 8) * N + n0 + col;
            #pragma unroll
            for (int j = 0; j < 8; ++j) br[c][j] = bp[(size_t)j * N];
        }
    };
    auto write_B = [&](int buf, float (&br)[CB][8]) {
        #pragma unroll
        for (int c = 0; c < CB; ++c) {
            int idx = c * 256 + tid;
            int col = idx & (BN - 1), q = idx / BN;
            unsigned int r0, r1, r2, r3;
            asm("v_cvt_pk_bf16_f32 %0, %1, %2" : "=v"(r0) : "v"(br[c][0]), "v"(br[c][1]));
            asm("v_cvt_pk_bf16_f32 %0, %1, %2" : "=v"(r1) : "v"(br[c][2]), "v"(br[c][3]));
            asm("v_cvt_pk_bf16_f32 %0, %1, %2" : "=v"(r2) : "v"(br[c][4]), "v"(br[c][5]));
            asm("v_cvt_pk_bf16_f32 %0, %1, %2" : "=v"(r3) : "v"(br[c][6]), "v"(br[c][7]));
            u32x4 r = {r0, r1, r2, r3};
            lB[buf][q][col] = __builtin_bit_cast(bf16x8, r);
        }
    };

    f32x4 acc[MF][NF] = {};
    float brX[CB][8], brY[CB][8];

    // ---- prologue: queue order [A0, A1, B0, B1] ----
    stage_A(0, 0);
    stage_A(1, 1);
    load_B(0, brX);
    load_B(1, brY);
    write_B(0, brX);                               // reg-dep drains B0 (and A0,A1)
    asm volatile("s_waitcnt vmcnt(16) lgkmcnt(0)" ::: "memory");
    __builtin_amdgcn_s_barrier();
    asm volatile("" ::: "memory");

    auto compute = [&](int k) {
        int sa = k % 3, bb = k & 1;
        bf16x8 af[MF], bfr[NF];
        #pragma unroll
        for (int m = 0; m < MF; ++m) af[m] = lA[sa][wm * MF * 16 + m * 16 + lrow][kg];
        #pragma unroll
        for (int n = 0; n < NF; ++n) bfr[n] = lB[bb][kg][wn * NF * 16 + n * 16 + lrow];
        #pragma unroll
        for (int m = 0; m < MF; ++m)
            #pragma unroll
            for (int n = 0; n < NF; ++n)
                acc[m][n] = __builtin_amdgcn_mfma_f32_16x16x32_bf16(
                    af[m], bfr[n], acc[m][n], 0, 0, 0);
    };

    // ---- main loop: all guards compile-time true ----
    for (int kb = 0; kb < MAIN; kb += 6) {
        #pragma unroll
        for (int c = 0; c < 6; ++c) {
            int k = kb + c;
            float (&brL)[CB][8] = ((c & 1) == 0) ? brX : brY;        // recv B(k+2)
            float (&brW)[CB][8] = (((c + 1) & 1) == 0) ? brX : brY;  // hold B(k+1)
            stage_A(k + 2, (k + 2) % 3);
            load_B(k + 2, brL);
            compute(k);
            write_B((k + 1) & 1, brW);
            asm volatile("s_waitcnt vmcnt(18) lgkmcnt(0)" ::: "memory");
            __builtin_amdgcn_s_barrier();
            asm volatile("" ::: "memory");
        }
    }

    // ---- tail: MAIN..NK-1 (2 or 4 iters), guards fold at unroll ----
    #pragma unroll
    for (int c = MAIN; c < NK; ++c) {
        float (&brL)[CB][8] = ((c & 1) == 0) ? brX : brY;
        float (&brW)[CB][8] = (((c + 1) & 1) == 0) ? brX : brY;
        if (c + 2 < NK) {
            stage_A(c + 2, (c + 2) % 3);
            load_B(c + 2, brL);
        }
        compute(c);
        if (c + 1 < NK) write_B((c + 1) & 1, brW);
        asm volatile("s_waitcnt vmcnt(0) lgkmcnt(0)" ::: "memory");
        __builtin_amdgcn_s_barrier();
        asm volatile("" ::: "memory");
    }

    // ---- epilogue ----
    #pragma unroll
    for (int n = 0; n < NF; ++n) {
        int col = n0 + wn * NF * 16 + n * 16 + lrow;
        #pragma unroll
        for (int m = 0; m < MF; ++m) {
            int rbase = m0 + wm * MF * 16 + m * 16 + kg * 4;
            #pragma unroll
            for (int i = 0; i < 4; ++i) {
                float v = acc[m][n][i] + bv[n];
                if (RELU) v = fmaxf(v, 0.f);
                size_t idx = ((size_t)e * RP + rbase + i) * (size_t)N + col;
                if constexpr (ATOMIC) {
                    atomicAdd((float*)&C[idx], v);
                } else if constexpr (sizeof(OutT) == 2) {
                    ((unsigned short*)C)[idx] = f2bf(v);
                } else {
                    ((float*)C)[idx] = v;
                }
            }
        }
    }
}

// ---------------- scatter back ----------------
__global__ __launch_bounds__(256) void k_scatter(
    const float* __restrict__ y, const int* __restrict__ token_slot,
    float* __restrict__ out)
{
    int t = blockIdx.x;
    int slot = token_slot[t];
    float4* o = reinterpret_cast<float4*>(out + (size_t)t * DM);
    if (slot >= 0) {
        int e = slot / CAP, i = slot - e * CAP;
        o[threadIdx.x] = reinterpret_cast<const float4*>(
            y + ((size_t)e * RP + i) * DM)[threadIdx.x];
    } else {
        o[threadIdx.x] = make_float4(0.f, 0.f, 0.f, 0.f);
    }
}

extern "C" void kernel_launch(void* const* d_in, const int* in_sizes, int n_in,
                              void* d_out, int out_size, void* d_ws, size_t ws_size,
                              hipStream_t stream)
{
    const float* x  = (const float*)d_in[0];
    const float* rw = (const float*)d_in[1];
    const float* rb = (const float*)d_in[2];
    const float* w1 = (const float*)d_in[3];
    const float* b1 = (const float*)d_in[4];
    const float* w2 = (const float*)d_in[5];
    const float* b2 = (const float*)d_in[6];
    float* out = (float*)d_out;

    char* ws = (char*)d_ws;
    int*   eidx       = (int*)(ws);                        // 16384 int
    int*   token_slot = (int*)(ws + 65536);                // 16384 int
    int*   s2t        = (int*)(ws + 131072);               // 2560 int
    int*   counts     = (int*)(ws + 141312);               // 8 int
    float* sumprob    = (float*)(ws + 141376);             // 8 f32
    unsigned short* xb = (unsigned short*)(ws + 147456);                 // [NE][RP][DM] bf16 (6.29 MB)
    unsigned short* h  = (unsigned short*)(ws + 147456 + 6291456);       // [NE][RP][DFF] bf16 (25.2 MB)
    float*          y  = (float*)(ws + 147456 + 6291456 + 25165824);     // [NE][RP][DM] f32 (12.6 MB)

    hipLaunchKernelGGL(k_init, dim3(1), dim3(64), 0, stream, sumprob);
    hipLaunchKernelGGL(k_router, dim3(T_TOK / 256), dim3(256), 0, stream,
                       x, rw, rb, eidx, sumprob);
    hipLaunchKernelGGL(k_scan, dim3(NE), dim3(256), 0, stream,
                       eidx, token_slot, s2t, counts);
    hipLaunchKernelGGL(k_lb, dim3(1), dim3(64), 0, stream,
                       counts, sumprob, out + (size_t)T_TOK * DM);
    hipLaunchKernelGGL(k_gather, dim3(NE * RP), dim3(256), 0, stream, x, s2t, xb);

    // GEMM1: [8] 384x1024 @ 1024x4096 -> h (bf16), relu+bias
    hipLaunchKernelGGL((k_gemm<32, 1024, 4096, true, false, unsigned short>),
                       dim3(32, 3, 8), dim3(256), 0, stream, xb, w1, b1, h);

    // GEMM2: split-K=2, atomics into zeroed y; bias applied by kb0==0 half
    hipLaunchKernelGGL(k_zero, dim3(1024), dim3(256), 0, stream,
                       (float4*)y, NE * RP * DM / 4);
    hipLaunchKernelGGL((k_gemm<64, 4096, 1024, false, true, float>),
                       dim3(16, 3, 8), dim3(256), 0, stream, h, w2, b2, y);

    hipLaunchKernelGGL(k_scatter, dim3(T_TOK), dim3(256), 0, stream,
                       y, token_slot, out);
}